// Round 4
// baseline (95.217 us; speedup 1.0000x reference)
//
#include <hip/hip_runtime.h>
#include <hip/hip_bf16.h>

// Problem constants (match reference)
#define NN 1024
#define FF 256
#define DD 64
#define RR 11
#define EE 2048
#define ALPHA 0.2f
#define NB 256
#define TPB 512
#define EPT (EE / TPB)          // 4 edges per thread in P1
#define PQ_BLOCKS (NB - 65)     // blocks 65..255 compute pq
#define PQ_SLOTS (PQ_BLOCKS * 8)
#define PERM_CAP 2176           // >= 2048 + 11*7 padded

// ws byte offsets
//   0     : int bar[4] = {cnt0, flag0, cnt1, flag1}   (memset to 0 each call)
//   4096  : int ntiles
//   4352  : int perm[PERM_CAP]
//   16384 : float2 pq[RR*FF]
//   65536 : float xT[FF*NN]      (1 MB)
//   2 MB  : float cbuf[EE*FF]    (2 MB)

__device__ __forceinline__ void gridbarrier(int* cnt, int* flag) {
    __syncthreads();
    if (threadIdx.x == 0) {
        __threadfence();  // publish this block's global writes (device scope)
        int old = __hip_atomic_fetch_add(cnt, 1, __ATOMIC_ACQ_REL,
                                         __HIP_MEMORY_SCOPE_AGENT);
        if (old == NB - 1) {
            __hip_atomic_store(flag, 1, __ATOMIC_RELEASE,
                               __HIP_MEMORY_SCOPE_AGENT);
        } else {
            while (__hip_atomic_load(flag, __ATOMIC_ACQUIRE,
                                     __HIP_MEMORY_SCOPE_AGENT) == 0) {
                __builtin_amdgcn_s_sleep(1);
            }
        }
    }
    __syncthreads();
}

__global__ __launch_bounds__(TPB) void gat_persistent(
    const float* __restrict__ x, const float* __restrict__ W,
    const float* __restrict__ a, const int* __restrict__ src,
    const int* __restrict__ dst, const int* __restrict__ rel,
    float* __restrict__ out,
    int* __restrict__ bar, int* __restrict__ ntiles_p,
    int* __restrict__ perm, float2* __restrict__ pq,
    float* __restrict__ xT, float* __restrict__ cbuf) {

    const int b    = blockIdx.x;   // 0..255
    const int tid  = threadIdx.x;  // 0..511
    const int wid  = tid >> 6;     // 0..7
    const int lane = tid & 63;

    __shared__ float tile[64][65];         // transpose staging (16.6 KB)
    __shared__ int   hist[16], base_sh[16], off_sh[16];
    __shared__ float p_sh[RR], q_sh[RR];
    __shared__ float red_m[8], red_s[8];

    // ======================= Phase 0 =======================
    if (b < 64) {
        // transpose 64x64 tile: x[1024,256] -> xT[256,1024]
        int rt = b >> 2, ct = b & 3;       // row-tile 0..15, col-tile 0..3
        int ty = tid >> 6, tx = tid & 63;  // ty 0..7
        #pragma unroll
        for (int i = 0; i < 8; ++i) {
            int r = ty * 8 + i;            // 0..63
            tile[r][tx] = x[(size_t)(rt * 64 + r) * FF + ct * 64 + tx];
        }
        __syncthreads();
        #pragma unroll
        for (int i = 0; i < 8; ++i) {
            int fcol = ty * 8 + i;
            xT[(size_t)(ct * 64 + fcol) * NN + rt * 64 + tx] = tile[tx][fcol];
        }
    } else if (b == 64) {
        // counting sort of edges by relation, buckets padded to multiple of 8
        if (tid < 16) hist[tid] = 0;
        __syncthreads();
        for (int e = tid; e < EE; e += TPB) atomicAdd(&hist[rel[e]], 1);
        __syncthreads();
        if (tid == 0) {
            int acc = 0;
            for (int r = 0; r < RR; ++r) {
                base_sh[r] = acc;
                acc += (hist[r] + 7) & ~7;
            }
            *ntiles_p = acc >> 3;          // tiles of 8 edges
        }
        __syncthreads();
        for (int i = tid; i < PERM_CAP; i += TPB) perm[i] = -1;
        if (tid < 16) off_sh[tid] = base_sh[tid];
        __syncthreads();
        for (int e = tid; e < EE; e += TPB) {
            int r = rel[e];
            int pos = atomicAdd(&off_sh[r], 1);
            perm[pos] = e;
        }
    } else {
        // pq: wave-slot handles tasks (r,f): p = dot(W[r,f,:],a[:64]), q = dot(...,a[64:])
        int slot = (b - 65) * 8 + wid;
        for (int task = slot; task < RR * FF; task += PQ_SLOTS) {
            int r = task >> 8, f = task & 255;
            float w  = W[((size_t)r * FF + f) * DD + lane];
            float pa = w * a[lane];
            float qa = w * a[DD + lane];
            #pragma unroll
            for (int o = 32; o > 0; o >>= 1) {
                pa += __shfl_down(pa, o);
                qa += __shfl_down(qa, o);
            }
            if (lane == 0) pq[task] = make_float2(pa, qa);
        }
    }

    gridbarrier(&bar[0], &bar[1]);

    // ======================= Phase 1 =======================
    {
        const int f = b;
        if (tid < RR) {
            float2 v = pq[tid * FF + f];
            p_sh[tid] = v.x;
            q_sh[tid] = v.y;
        }
        __syncthreads();

        const float* __restrict__ xTf = xT + (size_t)f * NN;
        float vals[EPT], xd_v[EPT];
        float m = -INFINITY;
        #pragma unroll
        for (int k = 0; k < EPT; ++k) {
            int e = tid + k * TPB;
            int si = src[e], di = dst[e], r = rel[e];
            float xs = xTf[si];
            float xd = xTf[di];
            float v = xs * p_sh[r] + xd * q_sh[r];
            v = v > 0.0f ? v : ALPHA * v;
            vals[k] = v;
            xd_v[k] = xd;
            m = fmaxf(m, v);
        }
        #pragma unroll
        for (int o = 32; o > 0; o >>= 1) m = fmaxf(m, __shfl_down(m, o));
        if (lane == 0) red_m[wid] = m;
        __syncthreads();
        m = red_m[0];
        #pragma unroll
        for (int i = 1; i < 8; ++i) m = fmaxf(m, red_m[i]);

        float s = 0.0f;
        #pragma unroll
        for (int k = 0; k < EPT; ++k) {
            vals[k] = expf(vals[k] - m);
            s += vals[k];
        }
        #pragma unroll
        for (int o = 32; o > 0; o >>= 1) s += __shfl_down(s, o);
        if (lane == 0) red_s[wid] = s;
        __syncthreads();
        float st = red_s[0];
        #pragma unroll
        for (int i = 1; i < 8; ++i) st += red_s[i];
        float inv = 1.0f / st;

        #pragma unroll
        for (int k = 0; k < EPT; ++k) {
            int e = tid + k * TPB;
            cbuf[(size_t)e * FF + f] = vals[k] * inv * xd_v[k];
        }
    }

    gridbarrier(&bar[2], &bar[3]);

    // ======================= Phase 2 =======================
    {
        int ntiles = *ntiles_p;
        for (int t = b; t < ntiles; t += NB) {
            int e = perm[t * 8 + wid];
            if (e >= 0) {
                int r = rel[e];
                const float* __restrict__ Wr = W + (size_t)r * FF * DD;
                const float* __restrict__ ce = cbuf + (size_t)e * FF;
                int fg = lane >> 4;          // 0..3: f within a 4-group
                int dq = lane & 15;          // 0..15: d-quad
                float4 acc = make_float4(0.f, 0.f, 0.f, 0.f);
                #pragma unroll 8
                for (int fb = 0; fb < FF; fb += 4) {
                    int ff = fb + fg;
                    float c = ce[ff];
                    float4 w4 = *(const float4*)&Wr[(size_t)ff * DD + dq * 4];
                    acc.x = fmaf(c, w4.x, acc.x);
                    acc.y = fmaf(c, w4.y, acc.y);
                    acc.z = fmaf(c, w4.z, acc.z);
                    acc.w = fmaf(c, w4.w, acc.w);
                }
                #pragma unroll
                for (int o = 16; o <= 32; o <<= 1) {
                    acc.x += __shfl_xor(acc.x, o);
                    acc.y += __shfl_xor(acc.y, o);
                    acc.z += __shfl_xor(acc.z, o);
                    acc.w += __shfl_xor(acc.w, o);
                }
                if (fg == 0)
                    *(float4*)&out[(size_t)e * DD + dq * 4] = acc;
            }
        }
    }
}

extern "C" void kernel_launch(void* const* d_in, const int* in_sizes, int n_in,
                              void* d_out, int out_size, void* d_ws, size_t ws_size,
                              hipStream_t stream) {
    const float* x  = (const float*)d_in[0];   // [N, F]
    const float* W  = (const float*)d_in[1];   // [R, F, D]
    const float* a  = (const float*)d_in[2];   // [2*D]
    const int* src  = (const int*)d_in[3];     // [E]
    const int* dst  = (const int*)d_in[4];     // [E]
    const int* rel  = (const int*)d_in[5];     // [E]
    float* out      = (float*)d_out;           // [E*D]

    char* wsb = (char*)d_ws;
    int*    bar      = (int*)wsb;
    int*    ntiles_p = (int*)(wsb + 4096);
    int*    perm     = (int*)(wsb + 4352);
    float2* pq       = (float2*)(wsb + 16384);
    float*  xT       = (float*)(wsb + 65536);
    float*  cbuf     = (float*)(wsb + (1 << 21));

    // zero the barrier state every call (captured as a memset node)
    hipMemsetAsync(bar, 0, 256, stream);

    gat_persistent<<<NB, TPB, 0, stream>>>(x, W, a, src, dst, rel, out,
                                           bar, ntiles_p, perm, pq, xT, cbuf);
}

// Round 5
// 54.689 us; speedup vs baseline: 1.7411x; 1.7411x over previous
//
#include <hip/hip_runtime.h>
#include <hip/hip_bf16.h>

// Problem constants (match reference)
#define NN 1024
#define FF 256
#define DD 64
#define RR 11
#define EE 2048
#define ALPHA 0.2f
#define NB 256
#define TPB 512
#define EPT (EE / TPB)      // 4 edges per thread in phase 1
#define PERM_CAP 2176       // >= 2048 + 11*7 padding

// ws layout (bytes):
//   0     : int cnt              (memset to 0 each call — barrier arrival count)
//   256   : int ntiles
//   512   : int perm[PERM_CAP]
//   16384 : float cbuf[EE*FF]    (2 MB)

__global__ __launch_bounds__(TPB) void gat_fused1(
    const float* __restrict__ x, const float* __restrict__ W,
    const float* __restrict__ a, const int* __restrict__ src,
    const int* __restrict__ dst, const int* __restrict__ rel,
    float* __restrict__ out,
    int* __restrict__ cnt, int* __restrict__ ntiles_p,
    int* __restrict__ perm, float* __restrict__ cbuf) {

    const int b    = blockIdx.x;   // 0..255 == feature f
    const int tid  = threadIdx.x;  // 0..511
    const int wid  = tid >> 6;     // 0..7
    const int lane = tid & 63;

    __shared__ float p_sh[RR], q_sh[RR];
    __shared__ float red_m[8], red_s[8];
    __shared__ int   hist[16], off_sh[16];

    // ---- block 0 only: counting sort of edges by relation (buckets padded to 8)
    if (b == 0) {
        if (tid < 16) hist[tid] = 0;
        __syncthreads();
        for (int e = tid; e < EE; e += TPB) atomicAdd(&hist[rel[e]], 1);
        __syncthreads();
        if (tid == 0) {
            int acc = 0;
            for (int r = 0; r < RR; ++r) {
                off_sh[r] = acc;
                acc += (hist[r] + 7) & ~7;
            }
            *ntiles_p = acc >> 3;          // tiles of 8 edges
        }
        __syncthreads();
        for (int i = tid; i < PERM_CAP; i += TPB) perm[i] = -1;
        __syncthreads();
        for (int e = tid; e < EE; e += TPB) {
            int pos = atomicAdd(&off_sh[rel[e]], 1);
            perm[pos] = e;
        }
    }

    // ---- own-feature p/q: p[r]=dot(W[r,f,:],a[:64]), q[r]=dot(W[r,f,:],a[64:])
    const int f = b;
    for (int r = wid; r < RR; r += 8) {
        float w  = W[((size_t)r * FF + f) * DD + lane];
        float pa = w * a[lane];
        float qa = w * a[DD + lane];
        #pragma unroll
        for (int o = 32; o > 0; o >>= 1) {
            pa += __shfl_down(pa, o);
            qa += __shfl_down(qa, o);
        }
        if (lane == 0) { p_sh[r] = pa; q_sh[r] = qa; }
    }
    __syncthreads();

    // ---- scores for feature f over all edges (4/thread), softmax over edges
    float vals[EPT], xd_v[EPT];
    float m = -INFINITY;
    #pragma unroll
    for (int k = 0; k < EPT; ++k) {
        int e = tid + k * TPB;
        int si = src[e], di = dst[e], r = rel[e];
        float xs = x[(size_t)si * FF + f];
        float xd = x[(size_t)di * FF + f];
        float v = xs * p_sh[r] + xd * q_sh[r];
        v = v > 0.0f ? v : ALPHA * v;
        vals[k] = v;
        xd_v[k] = xd;
        m = fmaxf(m, v);
    }
    #pragma unroll
    for (int o = 32; o > 0; o >>= 1) m = fmaxf(m, __shfl_down(m, o));
    if (lane == 0) red_m[wid] = m;
    __syncthreads();
    m = red_m[0];
    #pragma unroll
    for (int i = 1; i < 8; ++i) m = fmaxf(m, red_m[i]);

    float s = 0.0f;
    #pragma unroll
    for (int k = 0; k < EPT; ++k) {
        vals[k] = expf(vals[k] - m);
        s += vals[k];
    }
    #pragma unroll
    for (int o = 32; o > 0; o >>= 1) s += __shfl_down(s, o);
    if (lane == 0) red_s[wid] = s;
    __syncthreads();
    float st = red_s[0];
    #pragma unroll
    for (int i = 1; i < 8; ++i) st += red_s[i];
    float inv = 1.0f / st;

    // fused coefficient c[e,f] = attn[e,f] * x[dst[e],f], e-major
    #pragma unroll
    for (int k = 0; k < EPT; ++k) {
        int e = tid + k * TPB;
        cbuf[(size_t)e * FF + f] = vals[k] * inv * xd_v[k];
    }

    // ---- cheap grid barrier: RELEASE arrival, RELAXED spin, ACQUIRE exit.
    // (R3's per-iteration agent-acquire spin caused an L2 inv/wb storm.)
    __syncthreads();
    if (tid == 0) {
        __hip_atomic_fetch_add(cnt, 1, __ATOMIC_RELEASE,
                               __HIP_MEMORY_SCOPE_AGENT);   // one wbl2/block
        while (__hip_atomic_load(cnt, __ATOMIC_RELAXED,
                                 __HIP_MEMORY_SCOPE_AGENT) < NB) {
            __builtin_amdgcn_s_sleep(2);                    // no cache ops in loop
        }
        __builtin_amdgcn_fence(__ATOMIC_ACQUIRE, "agent");  // one inv/block
    }
    __syncthreads();

    // ---- phase 2: relation-sorted, one wave per edge
    {
        int ntiles = *ntiles_p;
        for (int t = b; t < ntiles; t += NB) {
            int e = perm[t * 8 + wid];
            if (e >= 0) {
                int r = rel[e];
                const float* __restrict__ Wr = W + (size_t)r * FF * DD;
                const float* __restrict__ ce = cbuf + (size_t)e * FF;
                int fg = lane >> 4;          // 0..3: f within a 4-group
                int dq = lane & 15;          // 0..15: d-quad
                float4 acc = make_float4(0.f, 0.f, 0.f, 0.f);
                #pragma unroll 8
                for (int fb = 0; fb < FF; fb += 4) {
                    int ff = fb + fg;
                    float c = ce[ff];
                    float4 w4 = *(const float4*)&Wr[(size_t)ff * DD + dq * 4];
                    acc.x = fmaf(c, w4.x, acc.x);
                    acc.y = fmaf(c, w4.y, acc.y);
                    acc.z = fmaf(c, w4.z, acc.z);
                    acc.w = fmaf(c, w4.w, acc.w);
                }
                #pragma unroll
                for (int o = 16; o <= 32; o <<= 1) {
                    acc.x += __shfl_xor(acc.x, o);
                    acc.y += __shfl_xor(acc.y, o);
                    acc.z += __shfl_xor(acc.z, o);
                    acc.w += __shfl_xor(acc.w, o);
                }
                if (fg == 0)
                    *(float4*)&out[(size_t)e * DD + dq * 4] = acc;
            }
        }
    }
}

extern "C" void kernel_launch(void* const* d_in, const int* in_sizes, int n_in,
                              void* d_out, int out_size, void* d_ws, size_t ws_size,
                              hipStream_t stream) {
    const float* x  = (const float*)d_in[0];   // [N, F]
    const float* W  = (const float*)d_in[1];   // [R, F, D]
    const float* a  = (const float*)d_in[2];   // [2*D]
    const int* src  = (const int*)d_in[3];     // [E]
    const int* dst  = (const int*)d_in[4];     // [E]
    const int* rel  = (const int*)d_in[5];     // [E]
    float* out      = (float*)d_out;           // [E*D]

    char* wsb = (char*)d_ws;
    int*   cnt      = (int*)wsb;
    int*   ntiles_p = (int*)(wsb + 256);
    int*   perm     = (int*)(wsb + 512);
    float* cbuf     = (float*)(wsb + 16384);

    hipMemsetAsync(cnt, 0, 64, stream);   // reset barrier each call (graph-safe)
    gat_fused1<<<NB, TPB, 0, stream>>>(x, W, a, src, dst, rel, out,
                                       cnt, ntiles_p, perm, cbuf);
}

// Round 7
// 26.992 us; speedup vs baseline: 3.5277x; 2.0261x over previous
//
#include <hip/hip_runtime.h>
#include <hip/hip_bf16.h>

// Problem constants (match reference)
#define NN 1024
#define FF 256
#define DD 64
#define RR 11
#define EE 2048
#define ALPHA 0.2f
#define TPB 512
#define EPT (EE / TPB)      // 4 edges per thread in K1
#define PERM_CAP 2176       // >= 2048 + 11*7 padding
#define PQ_N (FF * RR)      // 2816
#define K2_GRID (PERM_CAP / 8)  // 272: ntiles <= 267, so <=1 tile per block

// ws layout (bytes):
//   0     : int ntiles
//   256   : int perm[PERM_CAP]       (8704 B)
//   12288 : float2 mxinv[FF]         (2 KB)    {m[f], 1/s[f]}
//   16384 : float2 pqT[FF*RR]        (22.5 KB) pqT[f*RR+r] = {p,q}
// All fully rewritten every call; kernel boundary is the device-wide sync.

// K1: block = feature f. Stage x column f to LDS; own p/q; scores+softmax
//     stats only (m, 1/s). Block 0 additionally counting-sorts edges by
//     relation into 8-padded buckets (perm, ntiles).
__global__ __launch_bounds__(TPB) void k1_stats(
    const float* __restrict__ x, const float* __restrict__ W,
    const float* __restrict__ a, const int* __restrict__ src,
    const int* __restrict__ dst, const int* __restrict__ rel,
    float2* __restrict__ pqT, float2* __restrict__ mxinv,
    int* __restrict__ perm, int* __restrict__ ntiles_p) {

    const int f    = blockIdx.x;   // 0..255
    const int tid  = threadIdx.x;  // 0..511
    const int wid  = tid >> 6;     // 0..7
    const int lane = tid & 63;

    __shared__ float xcol[NN];     // 4 KB: x[:, f]
    __shared__ float p_sh[RR], q_sh[RR];
    __shared__ float red_m[8], red_s[8];
    __shared__ int   hist[16], off_sh[16];

    // stage column f of x (1024 scattered L2 loads, once per block)
    for (int i = tid; i < NN; i += TPB) xcol[i] = x[(size_t)i * FF + f];

    // own-feature p/q: p[r]=dot(W[r,f,:],a[:64]), q[r]=dot(W[r,f,:],a[64:])
    for (int r = wid; r < RR; r += 8) {
        float w  = W[((size_t)r * FF + f) * DD + lane];
        float pa = w * a[lane];
        float qa = w * a[DD + lane];
        #pragma unroll
        for (int o = 32; o > 0; o >>= 1) {
            pa += __shfl_down(pa, o);
            qa += __shfl_down(qa, o);
        }
        if (lane == 0) { p_sh[r] = pa; q_sh[r] = qa; }
    }
    __syncthreads();   // xcol + p_sh/q_sh ready
    if (tid < RR) pqT[f * RR + tid] = make_float2(p_sh[tid], q_sh[tid]);

    // scores for all edges (4/thread) from LDS; softmax stats over edge axis
    float vals[EPT];
    float m = -INFINITY;
    #pragma unroll
    for (int k = 0; k < EPT; ++k) {
        int e = tid + k * TPB;
        float xs = xcol[src[e]];
        float xd = xcol[dst[e]];
        int r = rel[e];
        float v = xs * p_sh[r] + xd * q_sh[r];
        v = v > 0.0f ? v : ALPHA * v;
        vals[k] = v;
        m = fmaxf(m, v);
    }
    #pragma unroll
    for (int o = 32; o > 0; o >>= 1) m = fmaxf(m, __shfl_down(m, o));
    if (lane == 0) red_m[wid] = m;
    __syncthreads();
    m = red_m[0];
    #pragma unroll
    for (int i = 1; i < 8; ++i) m = fmaxf(m, red_m[i]);

    float s = 0.0f;
    #pragma unroll
    for (int k = 0; k < EPT; ++k) s += expf(vals[k] - m);
    #pragma unroll
    for (int o = 32; o > 0; o >>= 1) s += __shfl_down(s, o);
    if (lane == 0) red_s[wid] = s;
    __syncthreads();
    float st = red_s[0];
    #pragma unroll
    for (int i = 1; i < 8; ++i) st += red_s[i];

    if (tid == 0) mxinv[f] = make_float2(m, 1.0f / st);

    // block 0: counting sort of edges by relation (buckets padded to 8)
    if (f == 0) {
        if (tid < 16) hist[tid] = 0;
        __syncthreads();
        for (int e = tid; e < EE; e += TPB) atomicAdd(&hist[rel[e]], 1);
        __syncthreads();
        if (tid == 0) {
            int acc = 0;
            for (int r = 0; r < RR; ++r) {
                off_sh[r] = acc;
                acc += (hist[r] + 7) & ~7;
            }
            *ntiles_p = acc >> 3;      // tiles of 8 edges
        }
        __syncthreads();
        for (int i = tid; i < PERM_CAP; i += TPB) perm[i] = -1;
        __syncthreads();
        for (int e = tid; e < EE; e += TPB) {
            int pos = atomicAdd(&off_sh[rel[e]], 1);
            perm[pos] = e;
        }
    }
}

// K2: block = tile of 8 relation-sorted edges (one wave per edge, all 8 waves
//     share one relation -> W L1 reuse). Recomputes the fused coefficient
//     c = exp(v - m[f]) * inv[f] * x[dst,f] on the fly; float4 W loads;
//     shfl_xor reduce over the 4 f-groups.
__global__ __launch_bounds__(TPB) void k2_out(
    const float* __restrict__ x, const float* __restrict__ W,
    const int* __restrict__ src, const int* __restrict__ dst,
    const int* __restrict__ rel,
    const float2* __restrict__ pqT, const float2* __restrict__ mxinv,
    const int* __restrict__ perm, const int* __restrict__ ntiles_p,
    float* __restrict__ out) {

    const int t    = blockIdx.x;   // tile id, 0..271
    const int tid  = threadIdx.x;
    const int wid  = tid >> 6;
    const int lane = tid & 63;

    if (t >= *ntiles_p) return;

    __shared__ float2 pq_lds[PQ_N];   // 22.5 KB
    __shared__ float2 mx_lds[FF];     // 2 KB
    for (int i = tid; i < PQ_N; i += TPB) pq_lds[i] = pqT[i];
    if (tid < FF) mx_lds[tid] = mxinv[tid];
    __syncthreads();

    int e = perm[t * 8 + wid];
    if (e < 0) return;
    int r  = rel[e];
    int si = src[e], di = dst[e];
    const float* __restrict__ xrs = x + (size_t)si * FF;
    const float* __restrict__ xrd = x + (size_t)di * FF;
    const float* __restrict__ Wr  = W + (size_t)r * FF * DD;

    const int fg = lane >> 4;        // 0..3: f within a 4-group
    const int dq = lane & 15;        // 0..15: d-quad
    float4 acc = make_float4(0.f, 0.f, 0.f, 0.f);
    #pragma unroll 8
    for (int fb = 0; fb < FF; fb += 4) {
        int ff = fb + fg;
        float xs = xrs[ff];                     // L2-warm broadcast loads
        float xd = xrd[ff];
        float2 pqv = pq_lds[ff * RR + r];
        float2 mi  = mx_lds[ff];
        float v = xs * pqv.x + xd * pqv.y;
        v = v > 0.0f ? v : ALPHA * v;
        float c = expf(v - mi.x) * mi.y * xd;   // attn[e,f] * x[dst,f]
        float4 w4 = *(const float4*)&Wr[(size_t)ff * DD + dq * 4];
        acc.x = fmaf(c, w4.x, acc.x);
        acc.y = fmaf(c, w4.y, acc.y);
        acc.z = fmaf(c, w4.z, acc.z);
        acc.w = fmaf(c, w4.w, acc.w);
    }
    #pragma unroll
    for (int o = 16; o <= 32; o <<= 1) {
        acc.x += __shfl_xor(acc.x, o);
        acc.y += __shfl_xor(acc.y, o);
        acc.z += __shfl_xor(acc.z, o);
        acc.w += __shfl_xor(acc.w, o);
    }
    if (fg == 0)
        *(float4*)&out[(size_t)e * DD + dq * 4] = acc;
}

extern "C" void kernel_launch(void* const* d_in, const int* in_sizes, int n_in,
                              void* d_out, int out_size, void* d_ws, size_t ws_size,
                              hipStream_t stream) {
    const float* x  = (const float*)d_in[0];   // [N, F]
    const float* W  = (const float*)d_in[1];   // [R, F, D]
    const float* a  = (const float*)d_in[2];   // [2*D]
    const int* src  = (const int*)d_in[3];     // [E]
    const int* dst  = (const int*)d_in[4];     // [E]
    const int* rel  = (const int*)d_in[5];     // [E]
    float* out      = (float*)d_out;           // [E*D]

    char* wsb = (char*)d_ws;
    int*    ntiles_p = (int*)wsb;
    int*    perm     = (int*)(wsb + 256);
    float2* mxinv    = (float2*)(wsb + 12288);
    float2* pqT      = (float2*)(wsb + 16384);

    k1_stats<<<FF, TPB, 0, stream>>>(x, W, a, src, dst, rel,
                                     pqT, mxinv, perm, ntiles_p);
    k2_out<<<K2_GRID, TPB, 0, stream>>>(x, W, src, dst, rel,
                                        pqT, mxinv, perm, ntiles_p, out);
}